// Round 1
// baseline (457.208 us; speedup 1.0000x reference)
//
#include <hip/hip_runtime.h>
#include <stdint.h>

// Problem constants (from reference)
#define ROWS 4096
#define COLS 11008
#define NTOT (ROWS * COLS)          // 45,088,768
#define NV4  (NTOT / 4)             // 11,272,192  (COLS % 4 == 0 -> float4 never crosses rows)
#define COLS4 (COLS / 4)            // 2752

// high_num = int(n*0.1) = 4,508,876 ; k_lo = high_num//2
#define HIGH_NUM 4508876u
#define RANK_LO  (HIGH_NUM / 2u)            // 2,254,438  (1-indexed rank of low_thresh)
#define RANK_HI  ((unsigned)NTOT - HIGH_NUM / 2u)  // 42,834,330 (1-indexed rank of high_thresh)

__device__ __forceinline__ unsigned f2key(float f) {
    unsigned u = __float_as_uint(f);
    return (u & 0x80000000u) ? ~u : (u | 0x80000000u);
}

__device__ __forceinline__ float key2f(unsigned key) {
    unsigned u = (key & 0x80000000u) ? (key & 0x7fffffffu) : ~key;
    return __uint_as_float(u);
}

// ---------------- Pass 1: 4096-bucket histogram of top 12 key bits ----------------
__global__ void __launch_bounds__(256) hist12_kernel(const float* __restrict__ x,
                                                     unsigned* __restrict__ g_hist) {
    __shared__ unsigned h[4096];
    for (int i = threadIdx.x; i < 4096; i += blockDim.x) h[i] = 0u;
    __syncthreads();

    const float4* x4 = (const float4*)x;
    int stride = gridDim.x * blockDim.x;
    for (int j = blockIdx.x * blockDim.x + threadIdx.x; j < NV4; j += stride) {
        float4 v = x4[j];
        atomicAdd(&h[f2key(v.x) >> 20], 1u);
        atomicAdd(&h[f2key(v.y) >> 20], 1u);
        atomicAdd(&h[f2key(v.z) >> 20], 1u);
        atomicAdd(&h[f2key(v.w) >> 20], 1u);
    }
    __syncthreads();
    for (int i = threadIdx.x; i < 4096; i += blockDim.x) {
        unsigned c = h[i];
        if (c) atomicAdd(&g_hist[i], c);   // only ~500 buckets populated for normal data
    }
}

// ---------------- scan1: find candidate top-12 bucket + residual rank for both targets ----
__global__ void __launch_bounds__(256) scan1_kernel(const unsigned* __restrict__ g_hist,
                                                    unsigned* __restrict__ meta) {
    __shared__ unsigned part[256];
    int t = threadIdx.x;
    unsigned v[16];
    unsigned sum = 0u;
#pragma unroll
    for (int i = 0; i < 16; i++) { v[i] = g_hist[t * 16 + i]; sum += v[i]; }
    part[t] = sum;
    __syncthreads();
    for (int off = 1; off < 256; off <<= 1) {
        unsigned a = (t >= off) ? part[t - off] : 0u;
        __syncthreads();
        part[t] += a;
        __syncthreads();
    }
    unsigned incl = part[t];
    unsigned excl = incl - sum;
    unsigned ranks[2] = {RANK_LO, RANK_HI};
    for (int k = 0; k < 2; k++) {
        unsigned R = ranks[k];
        if (excl < R && incl >= R) {
            unsigned cum = excl;
            for (int i = 0; i < 16; i++) {
                if (cum + v[i] >= R) { meta[k * 2] = (unsigned)(t * 16 + i); meta[k * 2 + 1] = R - cum; break; }
                cum += v[i];
            }
        }
    }
}

// ---------------- Pass 2: low-20-bit histograms restricted to candidate buckets ----------
__global__ void __launch_bounds__(256) hist20_kernel(const float* __restrict__ x,
                                                     const unsigned* __restrict__ meta,
                                                     unsigned* __restrict__ hist2) {
    unsigned b_lo = meta[0];
    unsigned b_hi = meta[2];
    unsigned* hlo = hist2;
    unsigned* hhi = hist2 + (1u << 20);

    const float4* x4 = (const float4*)x;
    int stride = gridDim.x * blockDim.x;
    for (int j = blockIdx.x * blockDim.x + threadIdx.x; j < NV4; j += stride) {
        float4 v = x4[j];
        float f[4] = {v.x, v.y, v.z, v.w};
#pragma unroll
        for (int c = 0; c < 4; c++) {
            unsigned key = f2key(f[c]);
            unsigned top = key >> 20;
            unsigned low = key & 0xFFFFFu;
            if (top == b_lo) atomicAdd(&hlo[low], 1u);
            if (top == b_hi) atomicAdd(&hhi[low], 1u);
        }
    }
}

// ---------------- chunksum: 1024-entry chunk sums of hist2 (2048 chunks total) -----------
__global__ void __launch_bounds__(256) chunksum_kernel(const unsigned* __restrict__ hist2,
                                                       unsigned* __restrict__ csum) {
    int t = threadIdx.x;
    const unsigned* p = hist2 + (size_t)blockIdx.x * 1024;
    unsigned s = p[t] + p[t + 256] + p[t + 512] + p[t + 768];
    __shared__ unsigned red[256];
    red[t] = s;
    for (int off = 128; off > 0; off >>= 1) {
        __syncthreads();
        if (t < off) red[t] += red[t + off];
    }
    if (t == 0) csum[blockIdx.x] = red[0];
}

// ---------------- scan2: refine to exact 32-bit key, emit threshold floats ---------------
__global__ void __launch_bounds__(256) scan2_kernel(const unsigned* __restrict__ hist2,
                                                    const unsigned* __restrict__ csum,
                                                    const unsigned* __restrict__ meta,
                                                    float* __restrict__ thr) {
    __shared__ unsigned part[256];
    __shared__ unsigned s_c, s_r;
    int t = threadIdx.x;
    int tgt = blockIdx.x;   // 0 = low threshold, 1 = high threshold
    unsigned b = meta[tgt * 2];
    unsigned R = meta[tgt * 2 + 1];

    // Phase 1: scan 1024 chunk sums -> chunk index + residual rank
    const unsigned* cs = csum + tgt * 1024;
    unsigned v[4];
    unsigned sum = 0u;
#pragma unroll
    for (int i = 0; i < 4; i++) { v[i] = cs[t * 4 + i]; sum += v[i]; }
    part[t] = sum;
    __syncthreads();
    for (int off = 1; off < 256; off <<= 1) {
        unsigned a = (t >= off) ? part[t - off] : 0u;
        __syncthreads();
        part[t] += a;
        __syncthreads();
    }
    {
        unsigned incl = part[t], excl = incl - sum;
        if (excl < R && incl >= R) {
            unsigned cum = excl;
            for (int i = 0; i < 4; i++) {
                if (cum + v[i] >= R) { s_c = (unsigned)(t * 4 + i); s_r = R - cum; break; }
                cum += v[i];
            }
        }
    }
    __syncthreads();
    unsigned c = s_c;
    unsigned R2 = s_r;
    __syncthreads();

    // Phase 2: scan the 1024 entries of the chosen chunk -> final 10 bits
    const unsigned* hp = hist2 + (size_t)tgt * (1u << 20) + (size_t)c * 1024;
    unsigned w[4];
    unsigned sum2 = 0u;
#pragma unroll
    for (int i = 0; i < 4; i++) { w[i] = hp[t * 4 + i]; sum2 += w[i]; }
    part[t] = sum2;
    __syncthreads();
    for (int off = 1; off < 256; off <<= 1) {
        unsigned a = (t >= off) ? part[t - off] : 0u;
        __syncthreads();
        part[t] += a;
        __syncthreads();
    }
    {
        unsigned incl = part[t], excl = incl - sum2;
        if (excl < R2 && incl >= R2) {
            unsigned cum = excl;
            for (int i = 0; i < 4; i++) {
                if (cum + w[i] >= R2) {
                    unsigned j = (unsigned)(t * 4 + i);
                    unsigned key = (b << 20) | (c << 10) | j;
                    thr[tgt] = key2f(key);
                    break;
                }
                cum += w[i];
            }
        }
    }
}

// ---------------- Pass 3: elementwise dual qdq with select (branch-free) -----------------
__global__ void __launch_bounds__(256) quant_kernel(const float* __restrict__ x,
                                                    const float* __restrict__ sl_,
                                                    const float* __restrict__ zl_,
                                                    const float* __restrict__ sh_,
                                                    const float* __restrict__ zh_,
                                                    const float* __restrict__ thr,
                                                    float* __restrict__ out) {
    float lowT = thr[0];
    float highT = thr[1];
    const float4* x4 = (const float4*)x;
    float4* o4 = (float4*)out;
    int stride = gridDim.x * blockDim.x;
    for (int j = blockIdx.x * blockDim.x + threadIdx.x; j < NV4; j += stride) {
        int row = j / COLS4;
        float sl = sl_[row], zl = zl_[row];
        float sh = sh_[row], zh = zh_[row];
        float4 v = x4[j];
        float in[4] = {v.x, v.y, v.z, v.w};
        float r[4];
#pragma unroll
        for (int c = 0; c < 4; c++) {
            float xx = in[c];
            bool m = (xx > lowT) && (xx < highT);   // bulk -> 1-bit path
            float s  = m ? sl : sh;
            float z  = m ? zl : zh;
            float mq = m ? 1.0f : 255.0f;
            float q = rintf(xx / s) + z;            // IEEE div + nearest-even, matches JAX
            q = fminf(fmaxf(q, 0.0f), mq);
            r[c] = s * (q - z);
        }
        o4[j] = make_float4(r[0], r[1], r[2], r[3]);
    }
}

extern "C" void kernel_launch(void* const* d_in, const int* in_sizes, int n_in,
                              void* d_out, int out_size, void* d_ws, size_t ws_size,
                              hipStream_t stream) {
    const float* x  = (const float*)d_in[0];
    const float* sl = (const float*)d_in[1];
    const float* zl = (const float*)d_in[2];
    const float* sh = (const float*)d_in[3];
    const float* zh = (const float*)d_in[4];
    float* out = (float*)d_out;

    // ws layout (u32 units): hist1[4096] | hist2[2*2^20] | csum[2048] | meta[8] | thr[2 floats]
    unsigned* hist1 = (unsigned*)d_ws;
    unsigned* hist2 = hist1 + 4096;
    unsigned* csum  = hist2 + 2 * (1u << 20);
    unsigned* meta  = csum + 2048;
    float*    thr   = (float*)(meta + 8);

    // zero hist1 + hist2 (ws is poisoned 0xAA before each call)
    size_t zero_bytes = (size_t)(4096 + 2 * (1u << 20)) * sizeof(unsigned);
    hipMemsetAsync(d_ws, 0, zero_bytes, stream);

    const int BLK = 256;
    const int GRID = 2048;   // 8 blocks/CU, grid-stride

    hist12_kernel<<<GRID, BLK, 0, stream>>>(x, hist1);
    scan1_kernel<<<1, BLK, 0, stream>>>(hist1, meta);
    hist20_kernel<<<GRID, BLK, 0, stream>>>(x, meta, hist2);
    chunksum_kernel<<<2048, BLK, 0, stream>>>(hist2, csum);
    scan2_kernel<<<2, BLK, 0, stream>>>(hist2, csum, meta, thr);
    quant_kernel<<<GRID, BLK, 0, stream>>>(x, sl, zl, sh, zh, thr, out);
}